// Round 16
// baseline (29.348 us; speedup 1.0000x reference)
//
#include <hip/hip_runtime.h>

#define N_NODES 4096
#define IN_DIM  128
#define OUT_DIM 32
#define HEADS   4
#define FDIM    128   // OUT_DIM*HEADS
#define K1_ROWS 8
#define CAP     256   // per-ROW compacted capacity (mean 62.4, ~24 sigma)
#define NBITSBLK 2048
#define NPROJBLK (N_NODES / K1_ROWS)   // 512

// RNE float->bf16 pack of two values into one dword (lo = a, hi = b)
static __device__ __forceinline__ unsigned bf16pack(float a, float b) {
    unsigned ua = __float_as_uint(a), ub = __float_as_uint(b);
    ua = (ua + 0x7FFFu + ((ua >> 16) & 1u)) >> 16;
    ub = (ub + 0x7FFFu + ((ub >> 16) & 1u)) >> 16;
    return ua | (ub << 16);
}

// ---------------- Kernel 1 (fused grid): adj->bitmask stream  +  projection ----
// Blocks [0, 2048): PURE READ STREAM. Wave = 8 KB of adj (8 up-front float4
//   loads), 4 ballots/KB, one 32 B store/KB -> 2 MB bitmask. No LDS/barriers.
//   Word r*64+k, bit b <-> adj[r][(k>>2)*256 + b*4 + (k&3)].
// Blocks [2048, 2560): projection + folded weights (validated r5-r15):
//   E[j][h] = exp(s_j*scale);  Ybf[j][cp] = bf16pair(E*xp[2cp], E*xp[2cp+1])
__global__ __launch_bounds__(256, 8) void gat_prep(const float* __restrict__ adj,
                                                   const float* __restrict__ x,
                                                   const float* __restrict__ W,
                                                   const float* __restrict__ a,
                                                   unsigned long long* __restrict__ bits,
                                                   unsigned* __restrict__ Ybf,
                                                   float* __restrict__ Eg) {
    if (blockIdx.x < NBITSBLK) {
        // ---- bits part: pure stream, zero sync ----
        const int wv   = threadIdx.x >> 6;
        const int lane = threadIdx.x & 63;
        const size_t wj = (size_t)blockIdx.x * 4 + wv;   // wave-job 0..8191
        const float4* A4 = (const float4*)adj;

        float4 v[8];                        // 8 KB in flight
#pragma unroll
        for (int it = 0; it < 8; ++it)
            v[it] = A4[(wj * 8 + it) * 64 + lane];

#pragma unroll
        for (int it = 0; it < 8; ++it) {
            const unsigned long long m0 = __ballot(v[it].x != 0.f);
            const unsigned long long m1 = __ballot(v[it].y != 0.f);
            const unsigned long long m2 = __ballot(v[it].z != 0.f);
            const unsigned long long m3 = __ballot(v[it].w != 0.f);
            if (lane == 0) {
                unsigned long long* p = bits + (wj * 8 + it) * 4;
                p[0] = m0; p[1] = m1; p[2] = m2; p[3] = m3;
            }
        }
        return;
    }

    // ---- proj part ----
    __shared__ float xs[K1_ROWS * IN_DIM];   // 4 KB: x tile, then xp tile
    __shared__ float eS[K1_ROWS][HEADS];
    const int t    = threadIdx.x;
    const int row0 = (blockIdx.x - NBITSBLK) * K1_ROWS;

    ((float4*)xs)[t] = ((const float4*)(x + (size_t)row0 * IN_DIM))[t];
    __syncthreads();

    const int c  = t & 127;
    const int rg = t >> 7;
    const float* xb = xs + (rg * 4) * IN_DIM;

    float acc0 = 0.f, acc1 = 0.f, acc2 = 0.f, acc3 = 0.f;
#pragma unroll 4
    for (int k0 = 0; k0 < IN_DIM; k0 += 4) {
        const float w0 = W[(k0 + 0) * FDIM + c];
        const float w1 = W[(k0 + 1) * FDIM + c];
        const float w2 = W[(k0 + 2) * FDIM + c];
        const float w3 = W[(k0 + 3) * FDIM + c];
        const float4 x0 = *(const float4*)(xb + 0 * IN_DIM + k0);
        const float4 x1 = *(const float4*)(xb + 1 * IN_DIM + k0);
        const float4 x2 = *(const float4*)(xb + 2 * IN_DIM + k0);
        const float4 x3 = *(const float4*)(xb + 3 * IN_DIM + k0);
        acc0 = fmaf(x0.x, w0, fmaf(x0.y, w1, fmaf(x0.z, w2, fmaf(x0.w, w3, acc0))));
        acc1 = fmaf(x1.x, w0, fmaf(x1.y, w1, fmaf(x1.z, w2, fmaf(x1.w, w3, acc1))));
        acc2 = fmaf(x2.x, w0, fmaf(x2.y, w1, fmaf(x2.z, w2, fmaf(x2.w, w3, acc2))));
        acc3 = fmaf(x3.x, w0, fmaf(x3.y, w1, fmaf(x3.z, w2, fmaf(x3.w, w3, acc3))));
    }

    const int rb = rg * 4;
    __syncthreads();
    xs[(rb + 0) * FDIM + c] = acc0;
    xs[(rb + 1) * FDIM + c] = acc1;
    xs[(rb + 2) * FDIM + c] = acc2;
    xs[(rb + 3) * FDIM + c] = acc3;
    __syncthreads();

    if (t < K1_ROWS * HEADS) {
        const int r = t >> 2, h = t & 3;
        const float4* xr = (const float4*)(xs + r * FDIM + h * OUT_DIM);
        const float4* aj = (const float4*)a;
        float vj = 0.f;
#pragma unroll
        for (int q = 0; q < 8; ++q) {
            const float4 xv = xr[q], a0 = aj[q];
            vj += xv.x * a0.x + xv.y * a0.y + xv.z * a0.z + xv.w * a0.w;
        }
        const float e = __expf(vj * 0.17677669529663687f);   // 1/sqrt(32)
        eS[r][h] = e;
        Eg[(row0 + r) * HEADS + h] = e;
    }
    __syncthreads();

#pragma unroll
    for (int q = 0; q < 2; ++q) {
        const int idx = t + 256 * q;
        const int r   = idx >> 6;
        const int cp  = idx & 63;
        const float e = eS[r][cp >> 4];
        const float a0 = xs[r * FDIM + 2 * cp]     * e;
        const float a1 = xs[r * FDIM + 2 * cp + 1] * e;
        Ybf[(size_t)(row0 + r) * 64 + cp] = bf16pack(a0, a1);
    }
}

// ---------------- Kernel 2: bitmask -> extract -> 16-edges-in-flight gather ----
// One WAVE per row, ZERO barriers, no adj access. Row mask = 512 B (L2-hot).
// Extraction: lane k owns 64-bit word k (popcount + 6-step shfl_up prefix +
// local ctz writes). Gather (r14-proven): 16 lanes/edge, uint4 = full 256 B Y
// row per group, 4 edges/instruction, 16 edges in flight. Merge = 2 shfl_xor.
__global__ __launch_bounds__(256, 8) void gat_sum(const unsigned long long* __restrict__ bits,
                                                  const unsigned* __restrict__ Ybf,
                                                  const float* __restrict__ E,
                                                  float* __restrict__ out) {
    const int wv   = threadIdx.x >> 6;
    const int lane = threadIdx.x & 63;
    const int row  = blockIdx.x * 4 + wv;
    const int g    = lane >> 4;       // edge-group 0..3
    const int q    = lane & 15;       // dim-chunk: dims 8q..8q+7
    const int head = q >> 2;          // head of those dims

    __shared__ int seg_s[4][CAP + 16];   // 4.25 KB; +16 pad for tail int4 reads
    int* seg = seg_s[wv];

    // ---- extract edges from this row's 64 mask words ----
    const unsigned long long w64 = bits[(size_t)row * 64 + lane];
    const int pc = __popcll(w64);
    int inc = pc;                         // inclusive prefix over lanes
#pragma unroll
    for (int d = 1; d < 64; d <<= 1) {
        const int tt = __shfl_up(inc, d);
        if (lane >= d) inc += tt;
    }
    const int cnt = __shfl(inc, 63);
    {
        int p = inc - pc;                 // exclusive offset
        unsigned long long m = w64;
        const int cb = (lane >> 2) * 256 + (lane & 3);   // col = cb + 4*bit
        while (m) {
            const int b = __builtin_ctzll(m);
            m &= m - 1ULL;
            if (p < CAP) seg[p] = cb + b * 4;
            ++p;
        }
    }

    const uint4* Yv = (const uint4*)Ybf;   // Y row = 16 uint4
    float a0 = 0.f, a1 = 0.f, a2 = 0.f, a3 = 0.f;
    float a4 = 0.f, a5 = 0.f, a6 = 0.f, a7 = 0.f, z = 0.f;

#define ACC(u, ev)                                                            \
    {                                                                         \
        a0 += __uint_as_float((u).x << 16);                                   \
        a1 += __uint_as_float((u).x & 0xFFFF0000u);                           \
        a2 += __uint_as_float((u).y << 16);                                   \
        a3 += __uint_as_float((u).y & 0xFFFF0000u);                           \
        a4 += __uint_as_float((u).z << 16);                                   \
        a5 += __uint_as_float((u).z & 0xFFFF0000u);                           \
        a6 += __uint_as_float((u).w << 16);                                   \
        a7 += __uint_as_float((u).w & 0xFFFF0000u);                           \
        z  += (ev);                                                           \
    }

    if (__builtin_expect(cnt <= CAP, 1)) {
        int p = 0;
        for (; p + 16 <= cnt; p += 16) {          // 16 edges, 4 uint4 in flight
            const int4 jq = *(const int4*)&seg[p + 4 * g];
            const uint4 y0 = Yv[(size_t)jq.x * 16 + q];
            const uint4 y1 = Yv[(size_t)jq.y * 16 + q];
            const uint4 y2 = Yv[(size_t)jq.z * 16 + q];
            const uint4 y3 = Yv[(size_t)jq.w * 16 + q];
            const float e0 = E[(size_t)jq.x * 4 + head];
            const float e1 = E[(size_t)jq.y * 4 + head];
            const float e2 = E[(size_t)jq.z * 4 + head];
            const float e3 = E[(size_t)jq.w * 4 + head];
            ACC(y0, e0) ACC(y1, e1) ACC(y2, e2) ACC(y3, e3)
        }
        if (p < cnt) {                            // masked tail (<= 15 edges)
            const int eb = p + 4 * g;
            const int4 jq = *(const int4*)&seg[eb];
            const bool k0 = eb + 0 < cnt, k1 = eb + 1 < cnt;
            const bool k2 = eb + 2 < cnt, k3 = eb + 3 < cnt;
            const int j0 = k0 ? jq.x : 0, j1 = k1 ? jq.y : 0;
            const int j2 = k2 ? jq.z : 0, j3 = k3 ? jq.w : 0;
            const uint4 y0 = Yv[(size_t)j0 * 16 + q];
            const uint4 y1 = Yv[(size_t)j1 * 16 + q];
            const uint4 y2 = Yv[(size_t)j2 * 16 + q];
            const uint4 y3 = Yv[(size_t)j3 * 16 + q];
            const float e0 = E[(size_t)j0 * 4 + head];
            const float e1 = E[(size_t)j1 * 4 + head];
            const float e2 = E[(size_t)j2 * 4 + head];
            const float e3 = E[(size_t)j3 * 4 + head];
            if (k0) ACC(y0, e0)
            if (k1) ACC(y1, e1)
            if (k2) ACC(y2, e2)
            if (k3) ACC(y3, e3)
        }
    } else {
        // ---- exact fallback (statistically unreachable): broadcast each mask
        //      word, groups take every 4th edge ----
        int ep = 0;
        for (int k = 0; k < 64; ++k) {
            unsigned long long m = __shfl(w64, k);
            const int cbk = (k >> 2) * 256 + (k & 3);
            while (m) {
                const int b = __builtin_ctzll(m);
                m &= m - 1ULL;
                if ((ep & 3) == g) {
                    const int j = cbk + b * 4;
                    const uint4 y = Yv[(size_t)j * 16 + q];
                    const float e = E[(size_t)j * 4 + head];
                    ACC(y, e)
                }
                ++ep;
            }
        }
    }
#undef ACC

    // ---- merge the 4 edge-groups (same dims): 2 butterfly steps ----
#pragma unroll
    for (int off = 16; off < 64; off <<= 1) {
        a0 += __shfl_xor(a0, off);
        a1 += __shfl_xor(a1, off);
        a2 += __shfl_xor(a2, off);
        a3 += __shfl_xor(a3, off);
        a4 += __shfl_xor(a4, off);
        a5 += __shfl_xor(a5, off);
        a6 += __shfl_xor(a6, off);
        a7 += __shfl_xor(a7, off);
        z  += __shfl_xor(z, off);
    }

    if (lane < 16) {                      // all lanes hold totals; 16 write
        const float invZ = 1.0f / z;      // z > 0 (diagonal edge)
        float4 o0, o1;
        o0.x = a0 * invZ; o0.y = a1 * invZ; o0.z = a2 * invZ; o0.w = a3 * invZ;
        o1.x = a4 * invZ; o1.y = a5 * invZ; o1.z = a6 * invZ; o1.w = a7 * invZ;
        float4* orow = (float4*)(out + (size_t)row * FDIM + q * 8);
        orow[0] = o0;
        orow[1] = o1;
    }
}

extern "C" void kernel_launch(void* const* d_in, const int* in_sizes, int n_in,
                              void* d_out, int out_size, void* d_ws, size_t ws_size,
                              hipStream_t stream) {
    const float* x   = (const float*)d_in[0];
    const float* adj = (const float*)d_in[1];
    const float* W   = (const float*)d_in[2];
    const float* a   = (const float*)d_in[3];
    float* out = (float*)d_out;

    unsigned* Ybf = (unsigned*)d_ws;                       // 4096*64 dwords = 1 MB
    float*    E   = (float*)(Ybf + (size_t)N_NODES * 64);  // 64 KB
    unsigned long long* bits =
        (unsigned long long*)(E + (size_t)N_NODES * HEADS); // 4096*64*8B = 2 MB

    gat_prep<<<NBITSBLK + NPROJBLK, 256, 0, stream>>>(adj, x, W, a, bits, Ybf, E);
    gat_sum<<<N_NODES / 4, 256, 0, stream>>>(bits, Ybf, E, out);
}

// Round 17
// 26.963 us; speedup vs baseline: 1.0884x; 1.0884x over previous
//
#include <hip/hip_runtime.h>

#define N_NODES 4096
#define IN_DIM  128
#define OUT_DIM 32
#define HEADS   4
#define FDIM    128   // OUT_DIM*HEADS
#define K1_ROWS 8
#define CAP     192   // per-half-row compacted capacity (mean 30.7, ~29 sigma)

typedef float __attribute__((ext_vector_type(4))) fvec4;   // for nontemporal loads

// RNE float->bf16 pack of two values into one dword (lo = a, hi = b)
static __device__ __forceinline__ unsigned bf16pack(float a, float b) {
    unsigned ua = __float_as_uint(a), ub = __float_as_uint(b);
    ua = (ua + 0x7FFFu + ((ua >> 16) & 1u)) >> 16;
    ub = (ub + 0x7FFFu + ((ub >> 16) & 1u)) >> 16;
    return ua | (ub << 16);
}

// ---------------- Kernel 1: projection + folded weights -> packed bf16 Y ----------
// s_i cancels in softmax over j (validated r5-r16). Weights depend only on j:
//   E[j][h] = exp(s_j[j][h]*scale); Ybf[j][cp] = bf16pair(E*xp[2cp], E*xp[2cp+1])
// out[i] = (sum_edges Ybf[j]) / (sum_edges E[j]) -- pure sparse sum, f32 accum.
__global__ __launch_bounds__(256) void gat_proj(const float* __restrict__ x,
                                                const float* __restrict__ W,
                                                const float* __restrict__ a,
                                                unsigned* __restrict__ Ybf,
                                                float* __restrict__ Eg) {
    __shared__ float xs[K1_ROWS * IN_DIM];   // 4 KB: x tile, then reused as xp tile
    __shared__ float eS[K1_ROWS][HEADS];
    const int t    = threadIdx.x;
    const int row0 = blockIdx.x * K1_ROWS;

    ((float4*)xs)[t] = ((const float4*)(x + (size_t)row0 * IN_DIM))[t];
    __syncthreads();

    const int c  = t & 127;          // output column
    const int rg = t >> 7;           // 0..1 -> rows rg*4 .. rg*4+3
    const float* xb = xs + (rg * 4) * IN_DIM;

    float acc0 = 0.f, acc1 = 0.f, acc2 = 0.f, acc3 = 0.f;
#pragma unroll 4
    for (int k0 = 0; k0 < IN_DIM; k0 += 4) {
        const float w0 = W[(k0 + 0) * FDIM + c];
        const float w1 = W[(k0 + 1) * FDIM + c];
        const float w2 = W[(k0 + 2) * FDIM + c];
        const float w3 = W[(k0 + 3) * FDIM + c];
        const float4 x0 = *(const float4*)(xb + 0 * IN_DIM + k0);
        const float4 x1 = *(const float4*)(xb + 1 * IN_DIM + k0);
        const float4 x2 = *(const float4*)(xb + 2 * IN_DIM + k0);
        const float4 x3 = *(const float4*)(xb + 3 * IN_DIM + k0);
        acc0 = fmaf(x0.x, w0, fmaf(x0.y, w1, fmaf(x0.z, w2, fmaf(x0.w, w3, acc0))));
        acc1 = fmaf(x1.x, w0, fmaf(x1.y, w1, fmaf(x1.z, w2, fmaf(x1.w, w3, acc1))));
        acc2 = fmaf(x2.x, w0, fmaf(x2.y, w1, fmaf(x2.z, w2, fmaf(x2.w, w3, acc2))));
        acc3 = fmaf(x3.x, w0, fmaf(x3.y, w1, fmaf(x3.z, w2, fmaf(x3.w, w3, acc3))));
    }

    const int rb = rg * 4;
    __syncthreads();                      // everyone done reading x tile
    xs[(rb + 0) * FDIM + c] = acc0;       // reuse LDS as xp tile
    xs[(rb + 1) * FDIM + c] = acc1;
    xs[(rb + 2) * FDIM + c] = acc2;
    xs[(rb + 3) * FDIM + c] = acc3;
    __syncthreads();

    if (t < K1_ROWS * HEADS) {            // 32 threads: (row, head) pairs
        const int r = t >> 2, h = t & 3;
        const float4* xr = (const float4*)(xs + r * FDIM + h * OUT_DIM);
        const float4* aj = (const float4*)a;             // a[:32]
        float vj = 0.f;
#pragma unroll
        for (int q = 0; q < 8; ++q) {
            const float4 xv = xr[q], a0 = aj[q];
            vj += xv.x * a0.x + xv.y * a0.y + xv.z * a0.z + xv.w * a0.w;
        }
        const float e = __expf(vj * 0.17677669529663687f);   // 1/sqrt(32)
        eS[r][h] = e;
        Eg[(row0 + r) * HEADS + h] = e;
    }
    __syncthreads();

    // pack Ybf tile: 8 rows x 64 dwords (2 bf16 cols per dword)
#pragma unroll
    for (int q = 0; q < 2; ++q) {
        const int idx = t + 256 * q;          // 0..511
        const int r   = idx >> 6;
        const int cp  = idx & 63;             // dword index = dims (2cp, 2cp+1)
        const float e = eS[r][cp >> 4];
        const float a0 = xs[r * FDIM + 2 * cp]     * e;
        const float a1 = xs[r * FDIM + 2 * cp + 1] * e;
        Ybf[(size_t)(row0 + r) * 64 + cp] = bf16pack(a0, a1);
    }
}

// ---------------- Kernel 2: 2 waves/row, compaction + 16-edges-in-flight gather ----
// Wave pair per row; each wave scans HALF the adj row, ballot-compacts to its
// own LDS segment (no barrier). r17 change: the stream-once adj reads use
// NONTEMPORAL loads (nt/evict-first -> no L1/L2/L3 allocation for 64 MB of
// single-use data); Y/E gathers keep normal caching (heavily reused). Gather:
// 16 lanes/edge (uint4 = full 256B Y row per group), 4 edges/instruction,
// 16 edges in flight. Merge = 2 shfl_xor + LDS half-combine.
__global__ __launch_bounds__(256, 8) void gat_sum(const float* __restrict__ adj,
                                                  const unsigned* __restrict__ Ybf,
                                                  const float* __restrict__ E,
                                                  float* __restrict__ out) {
    const int tid  = threadIdx.x;
    const int wv   = tid >> 6;
    const int lane = tid & 63;
    const int row  = blockIdx.x * 2 + (wv >> 1);
    const int half = wv & 1;
    const int g    = lane >> 4;       // edge-group 0..3
    const int q    = lane & 15;       // dim-chunk: dims 8q..8q+7
    const int head = q >> 2;          // head of those dims

    __shared__ int   seg_s[4][CAP + 16];   // +16 pad: tail int4 reads stay in-bounds
    __shared__ float part[4][16][12];      // 3 KB ({8 dims, z} per lane-chunk, pad 12)

    const fvec4* arow = (const fvec4*)(adj + (size_t)row * N_NODES) + half * 512;
    const unsigned long long lt = (1ULL << lane) - 1ULL;
    int* seg = seg_s[wv];

    // ---- Phase 1: NONTEMPORAL half-row stream (8 KB coalesced), compact to LDS.
    //      v[] scoped: dead after this block -> low VGPR pressure in gather.
    int cnt;
    {
        fvec4 v[8];
#pragma unroll
        for (int c = 0; c < 8; ++c)
            v[c] = __builtin_nontemporal_load(arow + c * 64 + lane);

        int base = 0;
#pragma unroll
        for (int c = 0; c < 8; ++c) {
            const int cb = half * 2048 + c * 256 + lane * 4;
            const float vals[4] = {v[c].x, v[c].y, v[c].z, v[c].w};
#pragma unroll
            for (int m = 0; m < 4; ++m) {
                const unsigned long long mk = __ballot(vals[m] != 0.f);
                const int pos = base + __popcll(mk & lt);
                if (vals[m] != 0.f && pos < CAP) seg[pos] = cb + m;
                base += __popcll(mk);   // wave-uniform
            }
        }
        cnt = base;
    }

    const uint4* Yv = (const uint4*)Ybf;   // Y row = 16 uint4 (cached: reused)
    float a0 = 0.f, a1 = 0.f, a2 = 0.f, a3 = 0.f;
    float a4 = 0.f, a5 = 0.f, a6 = 0.f, a7 = 0.f, z = 0.f;

#define ACC(u, ev)                                                            \
    {                                                                         \
        a0 += __uint_as_float((u).x << 16);                                   \
        a1 += __uint_as_float((u).x & 0xFFFF0000u);                           \
        a2 += __uint_as_float((u).y << 16);                                   \
        a3 += __uint_as_float((u).y & 0xFFFF0000u);                           \
        a4 += __uint_as_float((u).z << 16);                                   \
        a5 += __uint_as_float((u).z & 0xFFFF0000u);                           \
        a6 += __uint_as_float((u).w << 16);                                   \
        a7 += __uint_as_float((u).w & 0xFFFF0000u);                           \
        z  += (ev);                                                           \
    }

    if (__builtin_expect(cnt <= CAP, 1)) {
        int p = 0;
        // ---- full rounds: 16 edges (4 per group), 4 uint4 loads in flight ----
        for (; p + 16 <= cnt; p += 16) {
            const int4 jq = *(const int4*)&seg[p + 4 * g];   // my group's 4 edges
            const uint4 y0 = Yv[(size_t)jq.x * 16 + q];
            const uint4 y1 = Yv[(size_t)jq.y * 16 + q];
            const uint4 y2 = Yv[(size_t)jq.z * 16 + q];
            const uint4 y3 = Yv[(size_t)jq.w * 16 + q];
            const float e0 = E[(size_t)jq.x * 4 + head];
            const float e1 = E[(size_t)jq.y * 4 + head];
            const float e2 = E[(size_t)jq.z * 4 + head];
            const float e3 = E[(size_t)jq.w * 4 + head];
            ACC(y0, e0) ACC(y1, e1) ACC(y2, e2) ACC(y3, e3)
        }
        // ---- masked tail round (<= 15 edges) ----
        if (p < cnt) {
            const int eb = p + 4 * g;
            const int4 jq = *(const int4*)&seg[eb];          // pad keeps this in-bounds
            const bool k0 = eb + 0 < cnt, k1 = eb + 1 < cnt;
            const bool k2 = eb + 2 < cnt, k3 = eb + 3 < cnt;
            const int j0 = k0 ? jq.x : 0, j1 = k1 ? jq.y : 0;
            const int j2 = k2 ? jq.z : 0, j3 = k3 ? jq.w : 0;
            const uint4 y0 = Yv[(size_t)j0 * 16 + q];
            const uint4 y1 = Yv[(size_t)j1 * 16 + q];
            const uint4 y2 = Yv[(size_t)j2 * 16 + q];
            const uint4 y3 = Yv[(size_t)j3 * 16 + q];
            const float e0 = E[(size_t)j0 * 4 + head];
            const float e1 = E[(size_t)j1 * 4 + head];
            const float e2 = E[(size_t)j2 * 4 + head];
            const float e3 = E[(size_t)j3 * 4 + head];
            if (k0) ACC(y0, e0)
            if (k1) ACC(y1, e1)
            if (k2) ACC(y2, e2)
            if (k3) ACC(y3, e3)
        }
    } else {
        // ---- exact fallback (statistically unreachable): RE-READ adj from
        //      global and extract serially; edges spread over groups by counter.
        int ep = 0;
        for (int c = 0; c < 8; ++c) {
            const fvec4 vv = arow[c * 64 + lane];
            const float vals[4] = {vv.x, vv.y, vv.z, vv.w};
#pragma unroll
            for (int m = 0; m < 4; ++m) {
                unsigned long long mask = __ballot(vals[m] != 0.f);
                while (mask) {
                    const int b = __builtin_ctzll(mask);
                    mask &= mask - 1ULL;
                    if ((ep & 3) == g) {
                        const int j = half * 2048 + c * 256 + b * 4 + m;
                        const uint4 y = Yv[(size_t)j * 16 + q];
                        const float e = E[(size_t)j * 4 + head];
                        ACC(y, e)
                    }
                    ++ep;
                }
            }
        }
    }
#undef ACC

    // ---- merge the 4 edge-groups (same dims): 2 butterfly steps ----
#pragma unroll
    for (int off = 16; off < 64; off <<= 1) {
        a0 += __shfl_xor(a0, off);
        a1 += __shfl_xor(a1, off);
        a2 += __shfl_xor(a2, off);
        a3 += __shfl_xor(a3, off);
        a4 += __shfl_xor(a4, off);
        a5 += __shfl_xor(a5, off);
        a6 += __shfl_xor(a6, off);
        a7 += __shfl_xor(a7, off);
        z  += __shfl_xor(z, off);
    }

    if (lane < 16) {
        float* pr = part[wv][q];
        pr[0] = a0; pr[1] = a1; pr[2] = a2; pr[3] = a3;
        pr[4] = a4; pr[5] = a5; pr[6] = a6; pr[7] = a7;
        pr[8] = z;
    }
    __syncthreads();

    if ((wv & 1) == 0 && lane < 16) {     // waves 0,2 finalize their row
        const float* pa = part[wv][q];
        const float* pb = part[wv + 1][q];
        const float invZ = 1.0f / (pa[8] + pb[8]);   // > 0 (diagonal edge)
        float4 o0, o1;
        o0.x = (pa[0] + pb[0]) * invZ;
        o0.y = (pa[1] + pb[1]) * invZ;
        o0.z = (pa[2] + pb[2]) * invZ;
        o0.w = (pa[3] + pb[3]) * invZ;
        o1.x = (pa[4] + pb[4]) * invZ;
        o1.y = (pa[5] + pb[5]) * invZ;
        o1.z = (pa[6] + pb[6]) * invZ;
        o1.w = (pa[7] + pb[7]) * invZ;
        float4* orow = (float4*)(out + (size_t)row * FDIM + q * 8);
        orow[0] = o0;
        orow[1] = o1;
    }
}

extern "C" void kernel_launch(void* const* d_in, const int* in_sizes, int n_in,
                              void* d_out, int out_size, void* d_ws, size_t ws_size,
                              hipStream_t stream) {
    const float* x   = (const float*)d_in[0];
    const float* adj = (const float*)d_in[1];
    const float* W   = (const float*)d_in[2];
    const float* a   = (const float*)d_in[3];
    float* out = (float*)d_out;

    unsigned* Ybf = (unsigned*)d_ws;                       // 4096*64 dwords = 1 MB
    float*    E   = (float*)(Ybf + (size_t)N_NODES * 64);  // 64 KB

    gat_proj<<<N_NODES / K1_ROWS, 256, 0, stream>>>(x, W, a, Ybf, E);
    gat_sum<<<N_NODES / 2, 256, 0, stream>>>(adj, Ybf, E, out);
}